// Round 3
// baseline (5641.214 us; speedup 1.0000x reference)
//
#include <hip/hip_runtime.h>

// Workspace layout (floats), written by prep_kernel each call, then staged
// into LDS by every block of the main kernel. Weights feeding tanh are
// pre-scaled by K = 2*log2(e) so tanh(a) = 1 - 2/(1+exp2(a')) directly.
#define OFF_WIH 0      // 32   : W_ih[k]*K
#define OFF_C   32     // 32   : (b_ih[k]+b_hh[k])*K
#define OFF_WHH 64     // 1024 : transposed W_hh*K at [j*32 + k] = whh[k][j]*K
#define OFF_W1  1088   // 1536 : col-major W1 at [m*16 + o]
#define OFF_B1  2624   // 16
#define OFF_W2  2640   // 128  : col-major W2 at [k*8 + o]
#define OFF_B2  2768   // 8
#define OFF_W3  2776   // 8
#define OFF_B3  2784   // 1
#define WTOT    2785

typedef __fp16 h2f __attribute__((ext_vector_type(2)));

__global__ void prep_kernel(const float* __restrict__ wih, const float* __restrict__ whh,
                            const float* __restrict__ bih, const float* __restrict__ bhh,
                            const float* __restrict__ w1,  const float* __restrict__ b1,
                            const float* __restrict__ w2,  const float* __restrict__ b2,
                            const float* __restrict__ w3,  const float* __restrict__ b3,
                            float* __restrict__ ws)
{
    const float K = 2.8853900817779268f; // 2*log2(e)
    const int t = threadIdx.x;
    if (t < 32) {
        ws[OFF_WIH + t] = wih[t] * K;
        ws[OFF_C   + t] = (bih[t] + bhh[t]) * K;
    }
    for (int i = t; i < 1024; i += 256) {          // W_hh [32,32]: ws[j*32+k]=whh[k*32+j]*K
        int r = i >> 5, c = i & 31;
        ws[OFF_WHH + c * 32 + r] = whh[i] * K;
    }
    for (int i = t; i < 1536; i += 256) {          // W1 [16,96] -> col-major
        int o = i / 96, m = i - o * 96;
        ws[OFF_W1 + m * 16 + o] = w1[i];
    }
    if (t < 16) ws[OFF_B1 + t] = b1[t];
    for (int i = t; i < 128; i += 256) {           // W2 [8,16] -> col-major
        int o = i >> 4, k = i & 15;
        ws[OFF_W2 + k * 8 + o] = w2[i];
    }
    if (t < 8) { ws[OFF_B2 + t] = b2[t]; ws[OFF_W3 + t] = w3[t]; }
    if (t == 0) ws[OFF_B3] = b3[0];
}

// tanh(a) given ap = 2*log2(e)*a
__device__ __forceinline__ float tanh_fast(float ap) {
    float e = __builtin_amdgcn_exp2f(ap);
    return fmaf(-2.0f, __builtin_amdgcn_rcpf(e + 1.0f), 1.0f);
}

// One RNN timestep for 4 elements. hin/hout: packed-fp16 hidden state carrier.
// fc1 is accumulated immediately from the fp32 h (full precision on that path).
template<bool FIRST>
__device__ __forceinline__ void rnn_step(const float* __restrict__ W, int t,
                                         const float xt[4], const h2f hin[4][16],
                                         h2f hout[4][16], float f1[4][16])
{
    #pragma unroll
    for (int kt = 0; kt < 8; ++kt) {              // k-tiles of 4
        const int k0 = kt * 4;
        const float4 wih4 = *(const float4*)(W + OFF_WIH + k0);
        const float4 c4   = *(const float4*)(W + OFF_C   + k0);
        float acc[4][4];
        #pragma unroll
        for (int e = 0; e < 4; ++e) {
            acc[e][0] = fmaf(xt[e], wih4.x, c4.x);
            acc[e][1] = fmaf(xt[e], wih4.y, c4.y);
            acc[e][2] = fmaf(xt[e], wih4.z, c4.z);
            acc[e][3] = fmaf(xt[e], wih4.w, c4.w);
        }
        if (!FIRST) {
            #pragma unroll
            for (int j = 0; j < 32; ++j) {
                const float4 w4 = *(const float4*)(W + OFF_WHH + j * 32 + k0);
                #pragma unroll
                for (int e = 0; e < 4; ++e) {
                    const float hj = (float)hin[e][j >> 1][j & 1];
                    acc[e][0] = fmaf(hj, w4.x, acc[e][0]);
                    acc[e][1] = fmaf(hj, w4.y, acc[e][1]);
                    acc[e][2] = fmaf(hj, w4.z, acc[e][2]);
                    acc[e][3] = fmaf(hj, w4.w, acc[e][3]);
                }
            }
        }
        // tanh (in place) + pack carrier for next timestep
        #pragma unroll
        for (int e = 0; e < 4; ++e) {
            #pragma unroll
            for (int kk = 0; kk < 4; ++kk) acc[e][kk] = tanh_fast(acc[e][kk]);
            hout[e][(k0 >> 1) + 0] = __builtin_amdgcn_cvt_pkrtz(acc[e][0], acc[e][1]);
            hout[e][(k0 >> 1) + 1] = __builtin_amdgcn_cvt_pkrtz(acc[e][2], acc[e][3]);
        }
        // fc1 accumulation from fp32 h
        #pragma unroll
        for (int kk = 0; kk < 4; ++kk) {
            const float* w1p = W + OFF_W1 + (t * 32 + k0 + kk) * 16;
            float w1r[16];
            *(float4*)(w1r + 0)  = *(const float4*)(w1p + 0);
            *(float4*)(w1r + 4)  = *(const float4*)(w1p + 4);
            *(float4*)(w1r + 8)  = *(const float4*)(w1p + 8);
            *(float4*)(w1r + 12) = *(const float4*)(w1p + 12);
            #pragma unroll
            for (int e = 0; e < 4; ++e) {
                const float r = fmaxf(acc[e][kk], 0.0f);
                #pragma unroll
                for (int o = 0; o < 16; ++o)
                    f1[e][o] = fmaf(r, w1r[o], f1[e][o]);
            }
        }
    }
}

__global__ __launch_bounds__(256)
void rnn_mlp_kernel(const float* __restrict__ x, const float* __restrict__ ws,
                    float* __restrict__ out, int B)
{
    __shared__ __align__(16) float W[WTOT];
    for (int i = threadIdx.x; i < WTOT; i += 256) W[i] = ws[i];
    __syncthreads();

    const int tid = blockIdx.x * 256 + threadIdx.x;
    const int TOT = gridDim.x * 256;

    int es[4];
    bool val[4];
    #pragma unroll
    for (int e = 0; e < 4; ++e) { es[e] = tid + e * TOT; val[e] = es[e] < B; }

    float f1[4][16];
    {
        float b1r[16];
        *(float4*)(b1r + 0)  = *(const float4*)(W + OFF_B1 + 0);
        *(float4*)(b1r + 4)  = *(const float4*)(W + OFF_B1 + 4);
        *(float4*)(b1r + 8)  = *(const float4*)(W + OFF_B1 + 8);
        *(float4*)(b1r + 12) = *(const float4*)(W + OFF_B1 + 12);
        #pragma unroll
        for (int e = 0; e < 4; ++e)
            #pragma unroll
            for (int o = 0; o < 16; ++o) f1[e][o] = b1r[o];
    }

    h2f hA[4][16], hB[4][16];
    float xt[4];

    #pragma unroll
    for (int e = 0; e < 4; ++e) xt[e] = val[e] ? x[3 * es[e] + 0] : 0.0f;
    rnn_step<true>(W, 0, xt, hA, hA, f1);

    #pragma unroll
    for (int e = 0; e < 4; ++e) xt[e] = val[e] ? x[3 * es[e] + 1] : 0.0f;
    rnn_step<false>(W, 1, xt, hA, hB, f1);

    #pragma unroll
    for (int e = 0; e < 4; ++e) xt[e] = val[e] ? x[3 * es[e] + 2] : 0.0f;
    rnn_step<false>(W, 2, xt, hB, hA, f1);   // hA write is dead -> DCE

    // fc2 (16 -> 8)
    float g[4][8];
    {
        float b2r[8];
        *(float4*)(b2r + 0) = *(const float4*)(W + OFF_B2 + 0);
        *(float4*)(b2r + 4) = *(const float4*)(W + OFF_B2 + 4);
        #pragma unroll
        for (int e = 0; e < 4; ++e)
            #pragma unroll
            for (int o = 0; o < 8; ++o) g[e][o] = b2r[o];
    }
    #pragma unroll
    for (int k = 0; k < 16; ++k) {
        float w2r[8];
        *(float4*)(w2r + 0) = *(const float4*)(W + OFF_W2 + k * 8 + 0);
        *(float4*)(w2r + 4) = *(const float4*)(W + OFF_W2 + k * 8 + 4);
        #pragma unroll
        for (int e = 0; e < 4; ++e) {
            const float v = f1[e][k];
            #pragma unroll
            for (int o = 0; o < 8; ++o)
                g[e][o] = fmaf(v, w2r[o], g[e][o]);
        }
    }

    // fc3 (8 -> 1)
    float w3r[8];
    *(float4*)(w3r + 0) = *(const float4*)(W + OFF_W3 + 0);
    *(float4*)(w3r + 4) = *(const float4*)(W + OFF_W3 + 4);
    const float b3 = W[OFF_B3];
    #pragma unroll
    for (int e = 0; e < 4; ++e) {
        float y = b3;
        #pragma unroll
        for (int o = 0; o < 8; ++o)
            y = fmaf(fmaxf(g[e][o], 0.0f), w3r[o], y);
        if (val[e]) out[es[e]] = y;
    }
}

extern "C" void kernel_launch(void* const* d_in, const int* in_sizes, int n_in,
                              void* d_out, int out_size, void* d_ws, size_t ws_size,
                              hipStream_t stream)
{
    const float* x   = (const float*)d_in[0];
    const float* wih = (const float*)d_in[1];
    const float* whh = (const float*)d_in[2];
    const float* bih = (const float*)d_in[3];
    const float* bhh = (const float*)d_in[4];
    const float* w1  = (const float*)d_in[5];
    const float* b1  = (const float*)d_in[6];
    const float* w2  = (const float*)d_in[7];
    const float* b2  = (const float*)d_in[8];
    const float* w3  = (const float*)d_in[9];
    const float* b3  = (const float*)d_in[10];
    float* out = (float*)d_out;
    float* ws  = (float*)d_ws;

    const int B = in_sizes[0] / 3;
    const int nthreads = (B + 3) / 4;
    const int grid = (nthreads + 255) / 256;

    prep_kernel<<<1, 256, 0, stream>>>(wih, whh, bih, bhh, w1, b1, w2, b2, w3, b3, ws);
    rnn_mlp_kernel<<<grid, 256, 0, stream>>>(x, ws, out, B);
}